// Round 3
// baseline (4163.351 us; speedup 1.0000x reference)
//
#include <hip/hip_runtime.h>
#include <hip/hip_bf16.h>
#include <math.h>

// ---------------------------------------------------------------------------
// ViT forward (B=32, N=197, D=768, FF=3072, 12 layers) — round 2:
// overlapped 2-phase double-buffered MFMA GEMM (T3-minimum), fused QKV GEMM,
// XCD-bijective tile swizzle, buffer aliasing. f32 residual/LN/softmax.
// ---------------------------------------------------------------------------

namespace {
constexpr int DIM    = 768;
constexpr int FF_DIM = 3072;
constexpr int QKVN   = 2304;               // 3*DIM fused QKV output width
constexpr int NTOK   = 197;
constexpr int NBATCH = 32;
constexpr int NLAYER = 12;
constexpr int ROWS   = NBATCH * NTOK;      // 6304
constexpr int NPATCH = 196;
constexpr int PROWS  = NBATCH * NPATCH;    // 6272
constexpr int KVPAD  = 256;                // padded K for P@V GEMM
constexpr float LN_EPS = 1e-5f;
}

typedef __attribute__((ext_vector_type(8))) __bf16 bf16x8;
typedef __attribute__((ext_vector_type(4))) float  f32x4;

// ---------------- threefry2x32 gumbel (JAX jax.random.key(1)) ---------------
__device__ __forceinline__ unsigned rotl32(unsigned v, int d) {
  return (v << d) | (v >> (32 - d));
}

__device__ __forceinline__ float gumbel_noise(unsigned idx) {
  const unsigned ks0 = 0u, ks1 = 1u, ks2 = 0x1BD11BDBu;
  unsigned x0 = 0u + ks0;
  unsigned x1 = idx + ks1;
#define TFR(r) { x0 += x1; x1 = rotl32(x1, (r)); x1 ^= x0; }
  TFR(13) TFR(15) TFR(26) TFR(6)   x0 += ks1; x1 += ks2 + 1u;
  TFR(17) TFR(29) TFR(16) TFR(24)  x0 += ks2; x1 += ks0 + 2u;
  TFR(13) TFR(15) TFR(26) TFR(6)   x0 += ks0; x1 += ks1 + 3u;
  TFR(17) TFR(29) TFR(16) TFR(24)  x0 += ks1; x1 += ks2 + 4u;
  TFR(13) TFR(15) TFR(26) TFR(6)   x0 += ks2; x1 += ks0 + 5u;
#undef TFR
  unsigned bits = x0 ^ x1;
  float f = __uint_as_float((bits >> 9) | 0x3f800000u) - 1.0f;
  const float tiny = 1.17549435e-38f;
  float u = fmaxf(tiny, f + tiny);
  return -logf(-logf(u));
}

// ---------------- block reduction helpers ----------------------------------
__device__ __forceinline__ float block_reduce_sum(float val, float* red) {
  int tid = threadIdx.x;
  red[tid] = val; __syncthreads();
  for (int off = 128; off > 0; off >>= 1) {
    if (tid < off) red[tid] += red[tid + off];
    __syncthreads();
  }
  float r = red[0];
  __syncthreads();
  return r;
}

__device__ __forceinline__ float block_reduce_max(float val, float* red) {
  int tid = threadIdx.x;
  red[tid] = val; __syncthreads();
  for (int off = 128; off > 0; off >>= 1) {
    if (tid < off) red[tid] = fmaxf(red[tid], red[tid + off]);
    __syncthreads();
  }
  float r = red[0];
  __syncthreads();
  return r;
}

// ---------------- async 16B global -> LDS ----------------------------------
__device__ __forceinline__ void async_copy16(const void* g, void* l) {
  __builtin_amdgcn_global_load_lds(
      (const __attribute__((address_space(1))) unsigned*)g,
      (__attribute__((address_space(3))) unsigned*)l, 16, 0, 0);
}

// ---------------- bf16 MFMA GEMM (NT): C = A * B^T --------------------------
// A: [M][K] bf16 row-major (lda, batch stride sA)
// B: [N][K] bf16 row-major (ldb, batch stride sB)   <- "B^T" operand
// C: f32 (STORE=0) or bf16 (STORE=1)
// 128x128 tile, BK=64, 256 threads (4 waves as 2x2 of 64x64).
// Overlapped 2-phase: double-buffered LDS, STAGE(t+1) issued before compute(t),
// one __syncthreads per K-iter (compiler emits vmcnt(0)+lgkmcnt(0) at it).
// Grid: x = tilesM*tilesN (XCD-bijective swizzled), y = batch.
template<int STORE, bool GELU>
__global__ __launch_bounds__(256) void mm_nt(
    const __hip_bfloat16* __restrict__ A, long sA, int lda,
    const __hip_bfloat16* __restrict__ B, long sB, int ldb,
    void* __restrict__ Cv, long sC, int ldc,
    int M, int N, int K, const float* __restrict__ bias) {
  __shared__ __hip_bfloat16 As[2][128 * 64];
  __shared__ __hip_bfloat16 Bs[2][128 * 64];
  const int bz = blockIdx.y;
  A += (long)bz * sA;
  B += (long)bz * sB;

  // XCD-bijective tile swizzle (m204): same-A-panel tiles -> same XCD L2.
  const int tilesN = (N + 127) >> 7;
  const int nwg = gridDim.x;
  int id = blockIdx.x;
  {
    const int q = nwg >> 3, r = nwg & 7;
    const int xcd = id & 7, pos = id >> 3;
    id = (xcd < r ? xcd * (q + 1) : r * (q + 1) + (xcd - r) * q) + pos;
  }
  const int row0 = (id / tilesN) * 128, col0 = (id % tilesN) * 128;

  const int tid = threadIdx.x, lane = tid & 63, wid = tid >> 6;
  const int wr = (wid >> 1) * 64, wc = (wid & 1) * 64;
  const int fr = lane & 15;      // fragment row (A) / col (B) index
  const int kh = lane >> 4;      // k-chunk 0..3 (k offset kh*8)
  f32x4 acc[4][4] = {};

  const int elem = wid * 512 + lane * 8;  // within a 4KB chunk (2048 elems)

  auto stage = [&](int buf, int k0) {
    #pragma unroll
    for (int c = 0; c < 4; c++) {
      const int e = c * 2048 + elem;
      const int r = e >> 6, kk = e & 63;
      async_copy16(A + (long)(row0 + r) * lda + k0 + kk,
                   (char*)&As[buf][0] + c * 4096 + wid * 1024);
      async_copy16(B + (long)(col0 + r) * ldb + k0 + kk,
                   (char*)&Bs[buf][0] + c * 4096 + wid * 1024);
    }
  };

  const int nt = K >> 6;
  stage(0, 0);
  __syncthreads();
  int cur = 0;
  for (int t = 0; t < nt; ++t) {
    if (t + 1 < nt) stage(cur ^ 1, (t + 1) << 6);   // prefetch next tile
    #pragma unroll
    for (int ks = 0; ks < 2; ks++) {
      bf16x8 a[4], b[4];
      #pragma unroll
      for (int i = 0; i < 4; i++)
        a[i] = *(const bf16x8*)&As[cur][(wr + i * 16 + fr) * 64 + ks * 32 + kh * 8];
      #pragma unroll
      for (int j = 0; j < 4; j++)
        b[j] = *(const bf16x8*)&Bs[cur][(wc + j * 16 + fr) * 64 + ks * 32 + kh * 8];
      #pragma unroll
      for (int i = 0; i < 4; i++)
        #pragma unroll
        for (int j = 0; j < 4; j++)
          acc[i][j] = __builtin_amdgcn_mfma_f32_16x16x32_bf16(
              a[i], b[j], acc[i][j], 0, 0, 0);
    }
    __syncthreads();   // drains vmcnt(0) for stage(t+1) + lgkm; buffers safe
    cur ^= 1;
  }

  // epilogue: D layout col = lane&15, row = (lane>>4)*4 + reg
  #pragma unroll
  for (int i = 0; i < 4; i++) {
    #pragma unroll
    for (int j = 0; j < 4; j++) {
      #pragma unroll
      for (int t = 0; t < 4; t++) {
        const int r  = row0 + wr + i * 16 + kh * 4 + t;
        const int cc = col0 + wc + j * 16 + fr;
        if (r < M && cc < N) {
          float v = acc[i][j][t];
          if (bias) v += bias[cc];
          if (GELU) v = 0.5f * v * (1.0f + erff(v * 0.70710678118654752f));
          if (STORE == 0)
            ((float*)Cv)[(long)bz * sC + (long)r * ldc + cc] = v;
          else
            ((__hip_bfloat16*)Cv)[(long)bz * sC + (long)r * ldc + cc] =
                __float2bfloat16(v);
        }
      }
    }
  }
}

// ---------------- f32 [K][N] -> bf16 [N][K] transpose ------------------------
__global__ void transpose_bf16_kernel(const float* __restrict__ W,
                                      __hip_bfloat16* __restrict__ Wt,
                                      int K, int N) {
  __shared__ float t[32][33];
  const int k0 = blockIdx.x * 32, n0 = blockIdx.y * 32;
  const int tx = threadIdx.x & 31, ty = threadIdx.x >> 5;  // 32x8
  #pragma unroll
  for (int i = 0; i < 32; i += 8)
    t[ty + i][tx] = W[(long)(k0 + ty + i) * N + n0 + tx];
  __syncthreads();
  #pragma unroll
  for (int i = 0; i < 32; i += 8)
    Wt[(long)(n0 + ty + i) * K + k0 + tx] = __float2bfloat16(t[tx][ty + i]);
}

// ---------------- fused Wq/Wk/Wv transpose into one [2304][768] buffer ------
__global__ void transpose_qkv_kernel(const float* __restrict__ Wq,
                                     const float* __restrict__ Wk,
                                     const float* __restrict__ Wv,
                                     __hip_bfloat16* __restrict__ Wt) {
  __shared__ float t[32][33];
  const float* W = (blockIdx.z == 0) ? Wq : (blockIdx.z == 1) ? Wk : Wv;
  __hip_bfloat16* o = Wt + (long)blockIdx.z * DIM * DIM;
  const int k0 = blockIdx.x * 32, n0 = blockIdx.y * 32;
  const int tx = threadIdx.x & 31, ty = threadIdx.x >> 5;
  #pragma unroll
  for (int i = 0; i < 32; i += 8)
    t[ty + i][tx] = W[(long)(k0 + ty + i) * DIM + n0 + tx];
  __syncthreads();
  #pragma unroll
  for (int i = 0; i < 32; i += 8)
    o[(long)(n0 + ty + i) * DIM + k0 + tx] = __float2bfloat16(t[tx][ty + i]);
}

// ---------------- V slice -> vt[b][d][tok] (tok padded to 256 w/ zeros) -----
__global__ void vtrans_kernel(const __hip_bfloat16* __restrict__ qkv,
                              __hip_bfloat16* __restrict__ vt) {
  __shared__ __hip_bfloat16 s[64][68];
  const int b = blockIdx.z;
  const int t0 = blockIdx.x * 64;      // token tile (0..3 -> 256)
  const int d0 = blockIdx.y * 64;      // dim tile (0..11 -> 768)
  const int tx = threadIdx.x & 63, ty = threadIdx.x >> 6;  // 64 x 4
  for (int i = ty; i < 64; i += 4) {
    const int t = t0 + i;
    __hip_bfloat16 v = __float2bfloat16(0.f);
    if (t < NTOK) v = qkv[(long)(b * NTOK + t) * QKVN + 2 * DIM + d0 + tx];
    s[i][tx] = v;
  }
  __syncthreads();
  for (int i = ty; i < 64; i += 4)
    vt[((long)b * DIM + d0 + i) * KVPAD + t0 + tx] = s[tx][i];
}

// ---------------- patch embedding helpers -----------------------------------
__global__ void im2col_kernel(const float* __restrict__ x,
                              __hip_bfloat16* __restrict__ col) {
  const int p = blockIdx.x;              // b*196 + pidx
  const int b = p / NPATCH, pi = p % NPATCH;
  const int h = pi / 14, w = pi % 14;
  for (int e = threadIdx.x; e < DIM; e += 256) {
    const int c = e >> 8, r = e & 255, pp = r >> 4, q = r & 15;
    col[(long)p * DIM + e] = __float2bfloat16(
        x[(((long)b * 3 + c) * 224 + h * 16 + pp) * 224 + w * 16 + q]);
  }
}

__global__ void assemble_kernel(const float* __restrict__ tmp,
                                const float* __restrict__ cls,
                                const float* __restrict__ pos,
                                float* __restrict__ tok,
                                __hip_bfloat16* __restrict__ tok_bf) {
  const int row = blockIdx.x;            // 0..6303
  const int b = row / NTOK, n = row % NTOK;
  for (int d = threadIdx.x; d < DIM; d += 256) {
    float v = (n == 0) ? cls[d] : tmp[(long)(b * NPATCH + n - 1) * DIM + d];
    v += pos[n * DIM + d];
    tok[(long)row * DIM + d] = v;
    tok_bf[(long)row * DIM + d] = __float2bfloat16(v);
  }
}

// ---------------- fused gumbel + softmax ------------------------------------
__global__ void softmax_kernel(const float* __restrict__ sc,
                               __hip_bfloat16* __restrict__ P, int layer) {
  __shared__ float red[256];
  const int row = blockIdx.x;            // b*197 + n
  const int b = row / NTOK, n = row % NTOK;
  const int tid = threadIdx.x;
  const long base = (long)row * NTOK;
  const float inv_sqrt_d = 0.036084391824351615f;  // 1/sqrt(768)

  float x = -INFINITY;
  if (tid < NTOK) {
    const unsigned idx =
        ((((unsigned)layer * NBATCH + b) * NTOK + n) * NTOK) + tid;
    x = sc[base + tid] * inv_sqrt_d + gumbel_noise(idx);
  }
  const float mx = block_reduce_max(x, red);
  float ex = (tid < NTOK) ? expf(x - mx) : 0.f;
  const float s = block_reduce_sum(ex, red);
  const float pv = (tid < NTOK) ? ex / s : 0.f;
  P[(long)row * KVPAD + tid] = __float2bfloat16(pv);
}

// ---------------- residual add + LayerNorm (f32 + bf16 dual store) ----------
__global__ void add_ln_kernel(float* __restrict__ tok,
                              __hip_bfloat16* __restrict__ tok_bf,
                              const float* __restrict__ res,
                              const float* __restrict__ g,
                              const float* __restrict__ beta) {
  __shared__ float red[256];
  const int row = blockIdx.x;
  const int tid = threadIdx.x;
  const long base = (long)row * DIM;
  float v[3];
  float s = 0.f;
  #pragma unroll
  for (int i = 0; i < 3; i++) {
    const int d = tid + (i << 8);
    v[i] = tok[base + d] + res[base + d];
    s += v[i];
  }
  const float mean = block_reduce_sum(s, red) * (1.0f / DIM);
  float s2 = 0.f;
  #pragma unroll
  for (int i = 0; i < 3; i++) { const float dd = v[i] - mean; s2 += dd * dd; }
  const float var = block_reduce_sum(s2, red) * (1.0f / DIM);
  const float inv = 1.0f / sqrtf(var + LN_EPS);
  #pragma unroll
  for (int i = 0; i < 3; i++) {
    const int d = tid + (i << 8);
    const float o = (v[i] - mean) * inv * g[d] + beta[d];
    tok[base + d] = o;
    tok_bf[base + d] = __float2bfloat16(o);
  }
}

// ---------------- final LN (cls row) + head ---------------------------------
__global__ void head_kernel(const float* __restrict__ tok,
                            const float* __restrict__ g,
                            const float* __restrict__ beta,
                            const float* __restrict__ hw,
                            const float* __restrict__ hb,
                            float* __restrict__ out) {
  __shared__ float red[256];
  __shared__ float xn[DIM];
  const int b = blockIdx.x;
  const int tid = threadIdx.x;
  const float* xr = tok + (long)b * NTOK * DIM;   // cls row (n=0)
  float v[3];
  float s = 0.f;
  #pragma unroll
  for (int i = 0; i < 3; i++) { v[i] = xr[tid + (i << 8)]; s += v[i]; }
  const float mean = block_reduce_sum(s, red) * (1.0f / DIM);
  float s2 = 0.f;
  #pragma unroll
  for (int i = 0; i < 3; i++) { const float dd = v[i] - mean; s2 += dd * dd; }
  const float var = block_reduce_sum(s2, red) * (1.0f / DIM);
  const float inv = 1.0f / sqrtf(var + LN_EPS);
  #pragma unroll
  for (int i = 0; i < 3; i++) {
    const int d = tid + (i << 8);
    xn[d] = (v[i] - mean) * inv * g[d] + beta[d];
  }
  __syncthreads();
  for (int c = tid; c < 100; c += 256) {
    float acc = hb[c];
    for (int d = 0; d < DIM; d++) acc += xn[d] * hw[d * 100 + c];
    out[b * 100 + c] = acc;
  }
}

// ---------------------------------------------------------------------------
extern "C" void kernel_launch(void* const* d_in, const int* in_sizes, int n_in,
                              void* d_out, int out_size, void* d_ws, size_t ws_size,
                              hipStream_t stream) {
  const float* x        = (const float*)d_in[0];
  const float* patch_w  = (const float*)d_in[1];
  const float* patch_b  = (const float*)d_in[2];
  const float* cls_tok  = (const float*)d_in[3];
  const float* pos_emb  = (const float*)d_in[4];
  const float* Wq       = (const float*)d_in[5];
  const float* bq       = (const float*)d_in[6];
  const float* Wk       = (const float*)d_in[7];
  const float* bk       = (const float*)d_in[8];
  const float* Wv       = (const float*)d_in[9];
  const float* bv       = (const float*)d_in[10];
  const float* W1       = (const float*)d_in[11];
  const float* b1       = (const float*)d_in[12];
  const float* W2       = (const float*)d_in[13];
  const float* b2       = (const float*)d_in[14];
  const float* ln1_g    = (const float*)d_in[15];
  const float* ln1_b    = (const float*)d_in[16];
  const float* ln2_g    = (const float*)d_in[17];
  const float* ln2_b    = (const float*)d_in[18];
  const float* lnf_g    = (const float*)d_in[19];
  const float* lnf_b    = (const float*)d_in[20];
  const float* head_w   = (const float*)d_in[21];
  const float* head_b   = (const float*)d_in[22];
  float* out = (float*)d_out;

  // ---- workspace layout ----
  float* fb = (float*)d_ws;
  long fo = 0;
  float* tok    = fb + fo; fo += 6400L * DIM;        // f32 residual stream
  float* b4     = fb + fo; fo += 6400L * DIM;        // attn/ff2/patch out f32
  float* scbuf  = fb + fo; fo += 1241920L;           // scores f32 (32*197*197)
  __hip_bfloat16* hbuf = (__hip_bfloat16*)(fb + fo);
  long ho = 0;
  __hip_bfloat16* tok_bf = hbuf + ho; ho += 6400L * DIM;
  // big scratch: qkv [6368][2304] and ffout [6400][3072] alias (disjoint lifetime)
  __hip_bfloat16* qkv    = hbuf + ho;
  __hip_bfloat16* ffout  = hbuf + ho; ho += 6400L * FF_DIM;
  __hip_bfloat16* vt     = hbuf + ho; ho += (long)NBATCH * DIM * KVPAD;
  __hip_bfloat16* Pb     = hbuf + ho; ho += 6368L * KVPAD;
  __hip_bfloat16* wqkv_t = hbuf + ho; ho += (long)QKVN * DIM;
  __hip_bfloat16* w1_t   = hbuf + ho; ho += (long)FF_DIM * DIM;
  __hip_bfloat16* w2_t   = hbuf + ho; ho += (long)DIM * FF_DIM;

  const long DD = (long)DIM * DIM;
  const long QKVSTRIDE = (long)NTOK * QKVN;    // 453,888 (batch stride in qkv)
  const long TOKSTRIDE = (long)NTOK * DIM;     // 151,296
  const long SCSTRIDE  = (long)NTOK * NTOK;    // 38,809
  const long VTSTRIDE  = (long)DIM * KVPAD;    // 196,608
  const long PSTRIDE   = (long)NTOK * KVPAD;   // 50,432

  // ---- patch embedding ----
  im2col_kernel<<<PROWS, 256, 0, stream>>>(x, ffout);  // im2col into big scratch
  transpose_bf16_kernel<<<dim3(DIM / 32, DIM / 32), 256, 0, stream>>>(
      patch_w, wqkv_t, DIM, DIM);
  mm_nt<0, false><<<dim3((PROWS / 128) * (DIM / 128), 1), 256, 0, stream>>>(
      ffout, 0, DIM, wqkv_t, 0, DIM, b4, 0, DIM, PROWS, DIM, DIM, patch_b);
  assemble_kernel<<<ROWS, 256, 0, stream>>>(b4, cls_tok, pos_emb, tok, tok_bf);

  for (int l = 0; l < NLAYER; l++) {
    // weight transposes (f32 [K][N] -> bf16 [N][K])
    transpose_qkv_kernel<<<dim3(DIM / 32, DIM / 32, 3), 256, 0, stream>>>(
        Wq + l * DD, Wk + l * DD, Wv + l * DD, wqkv_t);
    transpose_bf16_kernel<<<dim3(DIM / 32, FF_DIM / 32), 256, 0, stream>>>(
        W1 + (long)l * DIM * FF_DIM, w1_t, DIM, FF_DIM);
    transpose_bf16_kernel<<<dim3(FF_DIM / 32, DIM / 32), 256, 0, stream>>>(
        W2 + (long)l * FF_DIM * DIM, w2_t, FF_DIM, DIM);

    // fused QKV: [6304][2304] = tok_bf @ wqkv_t^T  (+ concat bias via 3 slices)
    // bias: bq|bk|bv are separate; handle by three col-slice GEMMs? No —
    // single GEMM, bias pointer trick: we need bias[cc] for cc in [0,2304).
    // Build nothing: pass nullptr and add bias inside? Instead we exploit that
    // bq/bk/bv are contiguous per layer only within their own arrays.
    // -> use per-slice bias base selected by column inside epilogue is not
    //    possible with one pointer, so run 3 col-stripe dispatches? That
    //    reintroduces launches. Simplest: biases are tiny; fold them in the
    //    vtrans/scores path is wrong. We instead pre-gather the 2304-wide
    //    bias into scbuf tail (f32 scratch) once per layer with a 1-block copy.
    {
      // gather fused bias into f32 scratch (reuse end of scbuf area)
      float* bias_qkv = scbuf + 1241920L - 4096;
      hipMemcpyAsync(bias_qkv,            bq + l * DIM, DIM * 4,
                     hipMemcpyDeviceToDevice, stream);
      hipMemcpyAsync(bias_qkv + DIM,      bk + l * DIM, DIM * 4,
                     hipMemcpyDeviceToDevice, stream);
      hipMemcpyAsync(bias_qkv + 2 * DIM,  bv + l * DIM, DIM * 4,
                     hipMemcpyDeviceToDevice, stream);
      mm_nt<1, false><<<dim3(50 * (QKVN / 128), 1), 256, 0, stream>>>(
          tok_bf, 0, DIM, wqkv_t, 0, DIM, qkv, 0, QKVN,
          ROWS, QKVN, DIM, bias_qkv);
    }

    // V slice -> vt[b][d][tok] (zero-padded tok 197..255)
    vtrans_kernel<<<dim3(KVPAD / 64, DIM / 64, NBATCH), 256, 0, stream>>>(qkv, vt);

    // scores = Q @ K^T (f32), Q/K are lda=2304 slices of qkv
    mm_nt<0, false><<<dim3(2 * 2, NBATCH), 256, 0, stream>>>(
        qkv, QKVSTRIDE, QKVN, qkv + DIM, QKVSTRIDE, QKVN, scbuf, SCSTRIDE, NTOK,
        NTOK, NTOK, DIM, nullptr);

    softmax_kernel<<<ROWS, 256, 0, stream>>>(scbuf, Pb, l);

    // attn = P @ V   (NT with B = vt, K = KVPAD=256 zero-padded)
    mm_nt<0, false><<<dim3(2 * (DIM / 128), NBATCH), 256, 0, stream>>>(
        Pb, PSTRIDE, KVPAD, vt, VTSTRIDE, KVPAD, b4, TOKSTRIDE, DIM,
        NTOK, DIM, KVPAD, nullptr);

    add_ln_kernel<<<ROWS, 256, 0, stream>>>(tok, tok_bf, b4,
        ln1_g + l * DIM, ln1_b + l * DIM);

    // FF1 (+bias+GELU, bf16 out) — ffout aliases qkv (qkv dead after PV)
    mm_nt<1, true><<<dim3(50 * (FF_DIM / 128), 1), 256, 0, stream>>>(
        tok_bf, 0, DIM, w1_t, 0, DIM, ffout, 0, FF_DIM,
        ROWS, FF_DIM, DIM, b1 + l * FF_DIM);
    // FF2 (f32 out)
    mm_nt<0, false><<<dim3(50 * (DIM / 128), 1), 256, 0, stream>>>(
        ffout, 0, FF_DIM, w2_t, 0, FF_DIM, b4, 0, DIM,
        ROWS, DIM, FF_DIM, b2 + l * DIM);

    add_ln_kernel<<<ROWS, 256, 0, stream>>>(tok, tok_bf, b4,
        ln2_g + l * DIM, ln2_b + l * DIM);
  }

  head_kernel<<<NBATCH, 256, 0, stream>>>(tok, lnf_g, lnf_b, head_w, head_b, out);
}